// Round 6
// baseline (1175.684 us; speedup 1.0000x reference)
//
#include <hip/hip_runtime.h>
#include <stdint.h>

typedef unsigned short u16;
typedef unsigned int   u32;

typedef short s8v __attribute__((ext_vector_type(8)));
typedef short s4v __attribute__((ext_vector_type(4)));
typedef float f4v __attribute__((ext_vector_type(4)));

struct __align__(8) US4 { u16 x, y, z, w; };
struct __align__(8) U2  { u32 a, b; };

__device__ __forceinline__ u16 f2bf(float f) {
    union { float f; u32 u; } v; v.f = f;
    u32 u = v.u;
    return (u16)((u + 0x7fffu + ((u >> 16) & 1u)) >> 16);
}

// ---- asm-free bf16 round+pack (V_PERM_B32 builtin) ----
// round-half-away: bits+0x8000, max err 0.5 ULP (same bound as RNE, ties differ)
__device__ __forceinline__ u32 rbf(float x) { return __float_as_uint(x) + 0x8000u; }
// {low16 = bf16(lo), high16 = bf16(hi)} in 3 VALU ops
__device__ __forceinline__ u32 pkbf(float lo, float hi) {
    return __builtin_amdgcn_perm(rbf(hi), rbf(lo), 0x07060302u);
}
// {low16 = a.low16, high16 = b.low16}
__device__ __forceinline__ u32 pklo(u32 a, u32 b) {
    return __builtin_amdgcn_perm(b, a, 0x05040100u);
}
// {low16 = a.high16, high16 = b.high16}
__device__ __forceinline__ u32 pkhi(u32 a, u32 b) {
    return __builtin_amdgcn_perm(b, a, 0x07060302u);
}
__device__ __forceinline__ u32 bperm(u32 byteaddr, u32 src) {
    return (u32)__builtin_amdgcn_ds_bpermute((int)byteaddr, (int)src);
}

// 16x16x16 bf16 MFMA (gfx90a+, valid on gfx950)
#define MFMA16(a, b, c) __builtin_amdgcn_mfma_f32_16x16x16bf16_1k((a), (b), (c), 0, 0, 0)
// 16x16x32 bf16 MFMA (gfx950)
#define MFMA32(a, b, c) __builtin_amdgcn_mfma_f32_16x16x32_bf16((a), (b), (c), 0, 0, 0)

// ---------------------------------------------------------------------------
// Pack kernel (unchanged): weights -> bf16 MFMA A-fragment order; bias -> C-frag
// ---------------------------------------------------------------------------
__global__ void pack_kernel(const float* __restrict__ qkv_w, const float* __restrict__ proj_w,
                            const float* __restrict__ table, const int* __restrict__ ridx,
                            u16* __restrict__ pkQ, u16* __restrict__ pkP, float* __restrict__ biasP)
{
    int tid = blockIdx.x * 256 + threadIdx.x;
    if (tid < 24576) {
        int g = tid;
        int lane = g & 63, ks = (g >> 6) & 7, mt = g >> 9;
        int quad = lane >> 4, c = lane & 15;
        union { u16 h[8]; s8v v; } tmp;
#pragma unroll
        for (int j = 0; j < 8; ++j) {
            int kk = ks * 32 + quad * 8 + j;
            tmp.h[j] = f2bf(qkv_w[kk * 768 + mt * 16 + c]);
        }
        *(s8v*)&pkQ[g * 8] = tmp.v;
    } else if (tid < 32768) {
        int g = tid - 24576;
        int lane = g & 63, ks = (g >> 6) & 7, mt = g >> 9;
        int quad = lane >> 4, c = lane & 15;
        union { u16 h[8]; s8v v; } tmp;
#pragma unroll
        for (int j = 0; j < 8; ++j) {
            int kk = ks * 32 + quad * 8 + j;
            tmp.h[j] = f2bf(proj_w[kk * 256 + mt * 16 + c]);
        }
        *(s8v*)&pkP[g * 8] = tmp.v;
    } else if (tid < 49152) {
        int g = tid - 32768;
        int h = g >> 10, rest = (g >> 6) & 15, lane = g & 63;
        int mt = rest >> 2, nt = rest & 3;
        int quad = lane >> 4, c = lane & 15;
        int query = nt * 16 + c;
#pragma unroll
        for (int r = 0; r < 4; ++r) {
            int key = mt * 16 + quad * 4 + r;
            biasP[g * 4 + r] = table[ridx[query * 64 + key] * 16 + h];
        }
    }
}

// ---------------------------------------------------------------------------
// Main fused kernel: one block per 8x8 window. 512 threads = 8 waves, 2 heads/wave.
// Round 6: LDS cut 75,264 -> 38,400 B (3-4 blocks/CU):
//   - v transpose via in-wave ds_bpermute (vS eliminated)
//   - epilogue in proj C-frag layout (xf eliminated): scalar X re-read,
//     shfl-based post-LN stats, scalar stores. 7 barriers (was 9).
// ---------------------------------------------------------------------------
__global__ __launch_bounds__(512, 6)
void attn_win_kernel(const float* __restrict__ X,
                     const float* __restrict__ pre_g, const float* __restrict__ pre_b,
                     const float* __restrict__ post_g, const float* __restrict__ post_b,
                     const float* __restrict__ qkv_b, const float* __restrict__ proj_b,
                     const u16* __restrict__ pkQ, const u16* __restrict__ pkP,
                     const float* __restrict__ biasP,
                     float* __restrict__ out)
{
    // LDS carve-out (38,400 B total):
    //   [     0, 33792) xnS [64][264] bf16 token-major (xn; later attnout)
    //   [ 33792, 37888) pst [8][64][2] fp32 per-wave LN partials
    //   [ 37888, 38400) st  [64][2]    fp32 LN stats
    __shared__ __align__(16) unsigned char smem[38400];
    u16*   xnS = (u16*)smem;
    float* pst = (float*)(smem + 33792);
    float* st  = (float*)(smem + 37888);

    const int tid  = threadIdx.x;
    const int w    = tid >> 6;    // wave id 0..7
    const int l    = tid & 63;    // lane
    const int quad = l >> 4;
    const int cc   = l & 15;

    // XCD-contiguous window remap: each XCD gets 256 consecutive windows
    const int bidx = blockIdx.x;
    const int win  = ((bidx & 7) << 8) | (bidx >> 3);
    const int bb = win >> 10;
    const int wh = (win >> 5) & 31;
    const int ww = win & 31;
    const size_t base = (((size_t)bb * 256) * 256 + wh * 8) * 256 + ww * 8;

    const int ch0 = tid >> 4;          // 0..31
    const int t0  = (tid & 15) * 4;    // token group
    const int r0  = t0 >> 3, c0 = t0 & 7;

    // ---- phase 0a: coalesced window load into registers (channel-major) ----
    f4v xv[8];
#pragma unroll
    for (int it = 0; it < 8; ++it) {
        int ch = it * 32 + ch0;
        xv[it] = *(const f4v*)(X + base + (size_t)ch * 65536 + r0 * 256 + c0);
    }

    // ---- phase 0b: pre-LN stats from registers (quad-shfl + cross-wave LDS) ----
    {
        float s[4] = {0.f,0.f,0.f,0.f}, ss[4] = {0.f,0.f,0.f,0.f};
#pragma unroll
        for (int it = 0; it < 8; ++it)
#pragma unroll
            for (int j = 0; j < 4; ++j) { float x = xv[it][j]; s[j] += x; ss[j] += x * x; }
#pragma unroll
        for (int j = 0; j < 4; ++j) {
            s[j]  += __shfl_xor(s[j], 16, 64);  s[j]  += __shfl_xor(s[j], 32, 64);
            ss[j] += __shfl_xor(ss[j], 16, 64); ss[j] += __shfl_xor(ss[j], 32, 64);
        }
        if (quad == 0) {
#pragma unroll
            for (int j = 0; j < 4; ++j) {
                pst[(w * 64 + t0 + j) * 2]     = s[j];
                pst[(w * 64 + t0 + j) * 2 + 1] = ss[j];
            }
        }
    }
    __syncthreads();
    if (tid < 64) {
        float S = 0.f, SS = 0.f;
#pragma unroll
        for (int wv = 0; wv < 8; ++wv) {
            S  += pst[(wv * 64 + tid) * 2];
            SS += pst[(wv * 64 + tid) * 2 + 1];
        }
        float mean = S * (1.f / 256.f);
        float var  = SS * (1.f / 256.f) - mean * mean;
        st[tid * 2] = mean; st[tid * 2 + 1] = rsqrtf(var + 1e-5f);
    }
    __syncthreads();

    // ---- phase 0c: xn = LN(x)*g+b -> bf16 token-major (channel-pair packed b32) ----
    {
        float mean[4], rstd[4];
#pragma unroll
        for (int j = 0; j < 4; ++j) { mean[j] = st[(t0 + j) * 2]; rstd[j] = st[(t0 + j) * 2 + 1]; }
#pragma unroll
        for (int it = 0; it < 8; ++it) {
            int ch = it * 32 + ch0;
            float g = pre_g[ch], b = pre_b[ch];
            float y0 = (xv[it][0] - mean[0]) * rstd[0] * g + b;
            float y1 = (xv[it][1] - mean[1]) * rstd[1] * g + b;
            float y2 = (xv[it][2] - mean[2]) * rstd[2] * g + b;
            float y3 = (xv[it][3] - mean[3]) * rstd[3] * g + b;
            u32 m01 = pkbf(y0, y1);
            u32 m23 = pkbf(y2, y3);
            u32 p01 = __shfl_xor(m01, 16, 64);   // partner holds ch^1
            u32 p23 = __shfl_xor(m23, 16, 64);
            if ((quad & 1) == 0) {
                *(u32*)&xnS[(t0 + 0) * 264 + ch] = pklo(m01, p01);
                *(u32*)&xnS[(t0 + 1) * 264 + ch] = pkhi(m01, p01);
            } else {
                *(u32*)&xnS[(t0 + 2) * 264 + ch - 1] = pklo(p23, m23);
                *(u32*)&xnS[(t0 + 3) * 264 + ch - 1] = pkhi(p23, m23);
            }
        }
    }
    __syncthreads();

    // ---- phases 1+2 fused per head: barrier-free stretch ----
    // Wave w owns heads 2w, 2w+1. q/k stay in registers (frag identity);
    // v transposes in-wave via ds_bpermute (no LDS).
    u32 outbuf[2][4][2];
    const s8v* AQ = (const s8v*)pkQ;
#pragma unroll
    for (int hi = 0; hi < 2; ++hi) {
        const int head = w * 2 + hi;
        s4v qfr[4], kfr[4];
        u32 vp01[4], vp23[4];
        {
            f4v acc0[4], acc1[4], acc2[4];
#pragma unroll
            for (int nt = 0; nt < 4; ++nt) { acc0[nt] = 0.f; acc1[nt] = 0.f; acc2[nt] = 0.f; }
#pragma unroll
            for (int ks = 0; ks < 8; ++ks) {
                s8v bfr[4];
#pragma unroll
                for (int nt = 0; nt < 4; ++nt)
                    bfr[nt] = *(const s8v*)&xnS[(nt * 16 + cc) * 264 + ks * 32 + quad * 8];
                s8v a0 = AQ[((head     ) * 8 + ks) * 64 + l];
                s8v a1 = AQ[((head + 16) * 8 + ks) * 64 + l];
                s8v a2 = AQ[((head + 32) * 8 + ks) * 64 + l];
#pragma unroll
                for (int nt = 0; nt < 4; ++nt) {
                    acc0[nt] = MFMA32(a0, bfr[nt], acc0[nt]);
                    acc1[nt] = MFMA32(a1, bfr[nt], acc1[nt]);
                    acc2[nt] = MFMA32(a2, bfr[nt], acc2[nt]);
                }
            }
            // q epilogue: bias + l2norm -> qfr (registers)
            {
                float b0 = qkv_b[head * 16 + quad * 4 + 0];
                float b1 = qkv_b[head * 16 + quad * 4 + 1];
                float b2 = qkv_b[head * 16 + quad * 4 + 2];
                float b3 = qkv_b[head * 16 + quad * 4 + 3];
#pragma unroll
                for (int nt = 0; nt < 4; ++nt) {
                    f4v a = acc0[nt];
                    a[0] += b0; a[1] += b1; a[2] += b2; a[3] += b3;
                    float sq = (a[0]*a[0] + a[1]*a[1]) + (a[2]*a[2] + a[3]*a[3]);
                    sq += __shfl_xor(sq, 16, 64);
                    sq += __shfl_xor(sq, 32, 64);
                    float inv = 1.0f / fmaxf(sqrtf(sq), 1e-12f);
                    union { u32 d[2]; s4v v; } u;
                    u.d[0] = pkbf(a[0] * inv, a[1] * inv);
                    u.d[1] = pkbf(a[2] * inv, a[3] * inv);
                    qfr[nt] = u.v;
                }
            }
            // k epilogue: bias + l2norm -> kfr (registers)
            {
                float b0 = qkv_b[(head + 16) * 16 + quad * 4 + 0];
                float b1 = qkv_b[(head + 16) * 16 + quad * 4 + 1];
                float b2 = qkv_b[(head + 16) * 16 + quad * 4 + 2];
                float b3 = qkv_b[(head + 16) * 16 + quad * 4 + 3];
#pragma unroll
                for (int nt = 0; nt < 4; ++nt) {
                    f4v a = acc1[nt];
                    a[0] += b0; a[1] += b1; a[2] += b2; a[3] += b3;
                    float sq = (a[0]*a[0] + a[1]*a[1]) + (a[2]*a[2] + a[3]*a[3]);
                    sq += __shfl_xor(sq, 16, 64);
                    sq += __shfl_xor(sq, 32, 64);
                    float inv = 1.0f / fmaxf(sqrtf(sq), 1e-12f);
                    union { u32 d[2]; s4v v; } u;
                    u.d[0] = pkbf(a[0] * inv, a[1] * inv);
                    u.d[1] = pkbf(a[2] * inv, a[3] * inv);
                    kfr[nt] = u.v;
                }
            }
            // v epilogue: bias + pack to bf16 pairs (stay in C-frag layout)
            {
                float b0 = qkv_b[(head + 32) * 16 + quad * 4 + 0];
                float b1 = qkv_b[(head + 32) * 16 + quad * 4 + 1];
                float b2 = qkv_b[(head + 32) * 16 + quad * 4 + 2];
                float b3 = qkv_b[(head + 32) * 16 + quad * 4 + 3];
#pragma unroll
                for (int nt = 0; nt < 4; ++nt) {
                    f4v a = acc2[nt];
                    vp01[nt] = pkbf(a[0] + b0, a[1] + b1);
                    vp23[nt] = pkbf(a[2] + b2, a[3] + b3);
                }
            }
        }
        // attention for this head (q/k frags in regs; v via in-wave bpermute transpose)
        {
            // consumer (q,cc) wants v^T[head*16+cc][kt*16+4q+j] = producer lane
            // ((cc>>2)<<4)|(4q+j), pair reg j>>1 (=cc&2 side), half j&1 (=cc&1)
            s4v vfr[4];
            {
                u32 abase = (u32)((((cc >> 2) << 4) | (quad << 2)) << 2);
                u32 psel  = (cc & 1) ? 0x07060302u : 0x05040100u;
                bool useB = (cc & 2) != 0;
#pragma unroll
                for (int kt = 0; kt < 4; ++kt) {
                    u32 ra0 = bperm(abase,      vp01[kt]);
                    u32 ra1 = bperm(abase + 4,  vp01[kt]);
                    u32 ra2 = bperm(abase + 8,  vp01[kt]);
                    u32 ra3 = bperm(abase + 12, vp01[kt]);
                    u32 rb0 = bperm(abase,      vp23[kt]);
                    u32 rb1 = bperm(abase + 4,  vp23[kt]);
                    u32 rb2 = bperm(abase + 8,  vp23[kt]);
                    u32 rb3 = bperm(abase + 12, vp23[kt]);
                    u32 s0 = useB ? rb0 : ra0;
                    u32 s1 = useB ? rb1 : ra1;
                    u32 s2 = useB ? rb2 : ra2;
                    u32 s3 = useB ? rb3 : ra3;
                    union { u32 d[2]; s4v v; } u;
                    u.d[0] = __builtin_amdgcn_perm(s1, s0, psel);
                    u.d[1] = __builtin_amdgcn_perm(s3, s2, psel);
                    vfr[kt] = u.v;
                }
            }
            const f4v* BP = (const f4v*)biasP;
#pragma unroll
            for (int half = 0; half < 2; ++half) {
                f4v sT[4][2];
#pragma unroll
                for (int nt2 = 0; nt2 < 2; ++nt2) {
                    int nt = half * 2 + nt2;
#pragma unroll
                    for (int mt = 0; mt < 4; ++mt)
                        sT[mt][nt2] = MFMA16(kfr[mt], qfr[nt], BP[(head * 16 + mt * 4 + nt) * 64 + l]);
                }
#pragma unroll
                for (int nt2 = 0; nt2 < 2; ++nt2) {
                    int nt = half * 2 + nt2;
                    float m0 = fmaxf(fmaxf(sT[0][nt2][0], sT[0][nt2][1]), fmaxf(sT[0][nt2][2], sT[0][nt2][3]));
                    float m1 = fmaxf(fmaxf(sT[1][nt2][0], sT[1][nt2][1]), fmaxf(sT[1][nt2][2], sT[1][nt2][3]));
                    float m2 = fmaxf(fmaxf(sT[2][nt2][0], sT[2][nt2][1]), fmaxf(sT[2][nt2][2], sT[2][nt2][3]));
                    float m3 = fmaxf(fmaxf(sT[3][nt2][0], sT[3][nt2][1]), fmaxf(sT[3][nt2][2], sT[3][nt2][3]));
                    float mx = fmaxf(fmaxf(m0, m1), fmaxf(m2, m3));
                    mx = fmaxf(mx, __shfl_xor(mx, 16, 64));
                    mx = fmaxf(mx, __shfl_xor(mx, 32, 64));
                    float p[16];
                    float s4[4];
#pragma unroll
                    for (int mt = 0; mt < 4; ++mt) {
                        float e0 = __expf(sT[mt][nt2][0] - mx);
                        float e1 = __expf(sT[mt][nt2][1] - mx);
                        float e2 = __expf(sT[mt][nt2][2] - mx);
                        float e3 = __expf(sT[mt][nt2][3] - mx);
                        p[mt * 4 + 0] = e0; p[mt * 4 + 1] = e1;
                        p[mt * 4 + 2] = e2; p[mt * 4 + 3] = e3;
                        s4[mt] = (e0 + e1) + (e2 + e3);
                    }
                    float sum = (s4[0] + s4[1]) + (s4[2] + s4[3]);
                    sum += __shfl_xor(sum, 16, 64);
                    sum += __shfl_xor(sum, 32, 64);
                    float inv = 1.f / sum;
                    // PV with UNNORMALIZED P (bf16, values <= 1); scale output by inv after
                    f4v o = 0.f;
#pragma unroll
                    for (int kt = 0; kt < 4; ++kt) {
                        union { u32 d[2]; s4v v; } up;
                        up.d[0] = pkbf(p[kt * 4 + 0], p[kt * 4 + 1]);
                        up.d[1] = pkbf(p[kt * 4 + 2], p[kt * 4 + 3]);
                        o = MFMA16(vfr[kt], up.v, o);   // out^T[d][query] += v^T . P^T
                    }
                    outbuf[hi][nt][0] = pkbf(o[0] * inv, o[1] * inv);
                    outbuf[hi][nt][1] = pkbf(o[2] * inv, o[3] * inv);
                }
            }
        }
    }
    __syncthreads();   // all phase-1 xnS reads complete
#pragma unroll
    for (int hi = 0; hi < 2; ++hi)
#pragma unroll
        for (int nt = 0; nt < 4; ++nt) {
            U2 u2; u2.a = outbuf[hi][nt][0]; u2.b = outbuf[hi][nt][1];
            *(U2*)&xnS[(nt * 16 + cc) * 264 + (w * 2 + hi) * 16 + quad * 4] = u2;
        }
    __syncthreads();

    // ---- phase 3: proj^T GEMM (wave w -> m-tiles 2w, 2w+1) ----
    // X re-read in C-frag layout for the epilogue (issued early, L3-resident):
    // thread (w,q,cc): channels chA+j = 32w+4q+j, chB+j = chA+16+j; tokens nt*16+cc
    const int chA = w * 32 + quad * 4;
    const int chB = chA + 16;
    const float* Xe = X + base + (cc & 7) + ((cc >> 3) << 8);
    f4v xA[4], xB[4];   // [j] components = nt
#pragma unroll
    for (int j = 0; j < 4; ++j) {
        const float* pA = Xe + ((size_t)(chA + j) << 16);
        const float* pB = Xe + ((size_t)(chB + j) << 16);
#pragma unroll
        for (int nt = 0; nt < 4; ++nt) {
            xA[j][nt] = pA[nt << 9];
            xB[j][nt] = pB[nt << 9];
        }
    }
    f4v pa0[4], pa1[4];
#pragma unroll
    for (int nt = 0; nt < 4; ++nt) { pa0[nt] = 0.f; pa1[nt] = 0.f; }
    {
        const s8v* AP = (const s8v*)pkP;
#pragma unroll
        for (int ks = 0; ks < 8; ++ks) {
            s8v bfr[4];
#pragma unroll
            for (int nt = 0; nt < 4; ++nt)
                bfr[nt] = *(const s8v*)&xnS[(nt * 16 + cc) * 264 + ks * 32 + quad * 8];
            s8v a0 = AP[((w * 2    ) * 8 + ks) * 64 + l];
            s8v a1 = AP[((w * 2 + 1) * 8 + ks) * 64 + l];
#pragma unroll
            for (int nt = 0; nt < 4; ++nt) {
                pa0[nt] = MFMA32(a0, bfr[nt], pa0[nt]);
                pa1[nt] = MFMA32(a1, bfr[nt], pa1[nt]);
            }
        }
    }

    // ---- epilogue in C-frag layout: residual + post-LN stats + store ----
    f4v yA[4], yB[4];
#pragma unroll
    for (int j = 0; j < 4; ++j) {
        float pbA = proj_b[chA + j], pbB = proj_b[chB + j];
#pragma unroll
        for (int nt = 0; nt < 4; ++nt) {
            yA[j][nt] = xA[j][nt] + pa0[nt][j] + pbA;
            yB[j][nt] = xB[j][nt] + pa1[nt][j] + pbB;
        }
    }
    {
        float s[4], ss[4];
#pragma unroll
        for (int nt = 0; nt < 4; ++nt) {
            float sv = 0.f, sq = 0.f;
#pragma unroll
            for (int j = 0; j < 4; ++j) {
                float a = yA[j][nt], b = yB[j][nt];
                sv += a + b; sq += a * a + b * b;
            }
            s[nt] = sv; ss[nt] = sq;
        }
#pragma unroll
        for (int nt = 0; nt < 4; ++nt) {
            s[nt]  += __shfl_xor(s[nt], 16, 64);  s[nt]  += __shfl_xor(s[nt], 32, 64);
            ss[nt] += __shfl_xor(ss[nt], 16, 64); ss[nt] += __shfl_xor(ss[nt], 32, 64);
        }
        if (quad == 0) {
#pragma unroll
            for (int nt = 0; nt < 4; ++nt) {
                pst[(w * 64 + nt * 16 + cc) * 2]     = s[nt];
                pst[(w * 64 + nt * 16 + cc) * 2 + 1] = ss[nt];
            }
        }
    }
    __syncthreads();
    if (tid < 64) {
        float S = 0.f, SS = 0.f;
#pragma unroll
        for (int wv = 0; wv < 8; ++wv) {
            S  += pst[(wv * 64 + tid) * 2];
            SS += pst[(wv * 64 + tid) * 2 + 1];
        }
        float mean = S * (1.f / 256.f);
        float var  = SS * (1.f / 256.f) - mean * mean;
        st[tid * 2] = mean; st[tid * 2 + 1] = rsqrtf(var + 1e-5f);
    }
    __syncthreads();
    {
        float mean[4], rstd[4];
#pragma unroll
        for (int nt = 0; nt < 4; ++nt) {
            mean[nt] = st[(nt * 16 + cc) * 2];
            rstd[nt] = st[(nt * 16 + cc) * 2 + 1];
        }
        float* Oe = out + base + (cc & 7) + ((cc >> 3) << 8);
#pragma unroll
        for (int j = 0; j < 4; ++j) {
            float gA = post_g[chA + j], bA = post_b[chA + j];
            float gB = post_g[chB + j], bB = post_b[chB + j];
            float* pA = Oe + ((size_t)(chA + j) << 16);
            float* pB = Oe + ((size_t)(chB + j) << 16);
#pragma unroll
            for (int nt = 0; nt < 4; ++nt) {
                float a = yA[j][nt];
                float b = yB[j][nt];
                pA[nt << 9] = a + (a - mean[nt]) * rstd[nt] * gA + bA;
                pB[nt << 9] = b + (b - mean[nt]) * rstd[nt] * gB + bB;
            }
        }
    }
}

extern "C" void kernel_launch(void* const* d_in, const int* in_sizes, int n_in,
                              void* d_out, int out_size, void* d_ws, size_t ws_size,
                              hipStream_t stream)
{
    const float* X      = (const float*)d_in[0];
    const float* pre_g  = (const float*)d_in[1];
    const float* pre_b  = (const float*)d_in[2];
    const float* post_g = (const float*)d_in[3];
    const float* post_b = (const float*)d_in[4];
    const float* qkv_w  = (const float*)d_in[5];
    const float* qkv_b  = (const float*)d_in[6];
    const float* proj_w = (const float*)d_in[7];
    const float* proj_b = (const float*)d_in[8];
    const float* table  = (const float*)d_in[9];
    const int*   ridx   = (const int*)d_in[10];

    u16*   pkQ   = (u16*)d_ws;                          // 393,216 B
    u16*   pkP   = (u16*)((char*)d_ws + 393216);        // 131,072 B
    float* biasP = (float*)((char*)d_ws + 524288);      // 262,144 B

    pack_kernel<<<192, 256, 0, stream>>>(qkv_w, proj_w, table, ridx, pkQ, pkP, biasP);
    attn_win_kernel<<<2048, 512, 0, stream>>>(X, pre_g, pre_b, post_g, post_b,
                                              qkv_b, proj_b, pkQ, pkP, biasP,
                                              (float*)d_out);
}